// Round 6
// baseline (1116.257 us; speedup 1.0000x reference)
//
#include <hip/hip_runtime.h>
#include <hip/hip_bf16.h>
#include <math.h>

#define BB 8
#define SS 512
#define LIN_SCALE 0.044194173824159216f   // 1/sqrt(512)
#define CONV_SCALE 0.041666666666666664f  // 1/sqrt(64*9)
#define SQRT2 1.4142135623730951f

typedef __attribute__((ext_vector_type(8))) short short8;
typedef __attribute__((ext_vector_type(16))) float f32x16;

__device__ __forceinline__ ushort bf16h(float v) {
    unsigned u = __float_as_uint(v);
    return (ushort)((u + 0x7fffu + ((u >> 16) & 1u)) >> 16);
}
__device__ __forceinline__ void splitv(float v, ushort& h, ushort& l) {
    h = bf16h(v);
    l = bf16h(v - __uint_as_float((unsigned)h << 16));
}
__device__ __forceinline__ float b2f(ushort u) { return __uint_as_float((unsigned)u << 16); }

// ---------------------------------------------------------------------------
// prep kernels (unchanged layouts from R5)
// ---------------------------------------------------------------------------
__global__ void zero_k(float* z) { z[threadIdx.x] = 0.f; }   // 64 thr -> 256 B

__global__ __launch_bounds__(256) void tocl_k(const float* __restrict__ x,
                                              ushort* __restrict__ oH, ushort* __restrict__ oL) {
    __shared__ float tile[64][65];
    const int blk = blockIdx.x;                  // 8*256*4
    const int b = blk >> 10, rem = blk & 1023;
    const int y = rem >> 2, x0 = (rem & 3) << 6;
    const int tid = threadIdx.x, lane = tid & 63, g = tid >> 6;
    const float* xb = x + ((size_t)b << 22) + (y << 8) + x0;
    #pragma unroll
    for (int i = 0; i < 16; ++i) {
        int c = i * 4 + g;
        tile[c][lane] = xb[((size_t)c << 16) + lane];
    }
    __syncthreads();
    const size_t pixbase = ((size_t)b << 16) + (y << 8) + x0;
    #pragma unroll
    for (int i = 0; i < 16; ++i) {
        int xx = i * 4 + g;
        ushort h, l; splitv(tile[lane][xx], h, l);
        size_t idx = (pixbase + xx) * 64 + lane;
        oH[idx] = h; oL[idx] = l;
    }
}

// Weight image (ushort index): i = (((((c*3+dx)*3+dy)*2+pl)*64+co)*2+lh)*8 + e
__device__ __forceinline__ void wdecode(int i, int& c, int& tap, int& co, int& ci, int& pl) {
    int e = i & 7;  int t = i >> 3;
    int lh = t & 1; t >>= 1;
    co = t & 63;    t >>= 6;
    pl = t & 1;     t >>= 1;
    int dy = t % 3; t /= 3;
    int dx = t % 3; t /= 3;
    c = t;
    ci = c * 16 + lh * 8 + e;
    tap = dy * 3 + dx;
}

__global__ void packw_k(const float* __restrict__ w, ushort* __restrict__ img) {
    int i = blockIdx.x * 256 + threadIdx.x;      // 73728
    if (i >= 73728) return;
    int c, tap, co, ci, pl;
    wdecode(i, c, tap, co, ci, pl);
    ushort h, l; splitv(w[(co * 64 + ci) * 9 + tap], h, l);
    img[i] = pl ? l : h;
}

__global__ void style_s_k(const float* __restrict__ style, const float* __restrict__ mod_w,
                          const float* __restrict__ mod_b, float* __restrict__ sbuf) {
    int tid = threadIdx.x;                       // 512
    int b = tid >> 6, cin = tid & 63;
    float acc = 0.f;
    for (int j = 0; j < SS; ++j) acc += style[b * SS + j] * mod_w[cin * SS + j];
    sbuf[b * 64 + cin] = acc * LIN_SCALE + mod_b[cin];
}

__global__ void demod_k(const float* __restrict__ conv_w, const float* __restrict__ sbuf,
                        float* __restrict__ demod) {
    int tid = threadIdx.x;                       // 512
    int b = tid >> 6, cout = tid & 63;
    float sum = 0.f;
    for (int cin = 0; cin < 64; ++cin) {
        float m = CONV_SCALE * sbuf[b * 64 + cin];
        const float* wp = conv_w + (cout * 64 + cin) * 9;
        #pragma unroll
        for (int k = 0; k < 9; ++k) { float v = wp[k] * m; sum += v * v; }
    }
    demod[b * 64 + cout] = 1.0f / sqrtf(sum + 1e-8f);
}

__global__ void packmod_k(const float* __restrict__ conv_w, const float* __restrict__ sbuf,
                          const float* __restrict__ demod, ushort* __restrict__ img) {
    int i = blockIdx.x * 256 + threadIdx.x;      // 589824
    if (i >= 589824) return;
    int b = i / 73728, ii = i % 73728;
    int c, tap, co, ci, pl;
    wdecode(ii, c, tap, co, ci, pl);
    float v = CONV_SCALE * conv_w[(co * 64 + ci) * 9 + tap] * sbuf[b * 64 + ci] * demod[b * 64 + co];
    ushort h, l; splitv(v, h, l);
    img[i] = pl ? l : h;
}

// ---------------------------------------------------------------------------
// MFMA conv: 3x3 C64->C64 SAME. Pre-split bf16 H/L channels-last input.
// Block 256 thr = 4 waves; tile 8 rows x 32 px; 64 couts; per wave 2M x 2N
// 32x32x16 frags; K chunked 16 cins (12 phases of {c,dx}).
// A (weights): global->VGPR, register double-buffered one phase ahead.
// B (input): DMA double-buffered LDS (21760 B/chunk), slot permutation
//   sp = (k + (p>>1)) & 3  (k = pl*2+kh)  -> conflict-free ds_read_b128.
// One counted vmcnt(12)+barrier per chunk (DMA drain, A-prefetch kept).
// EPI: 0 = PReLU->pair, 1 = +resid(pair)->pair, 2 = fusedLReLU->NCHW fp32.
// ---------------------------------------------------------------------------
#define GLDS(gsrc, ldst) __builtin_amdgcn_global_load_lds( \
    (const __attribute__((address_space(1))) unsigned int*)(gsrc), \
    (__attribute__((address_space(3))) unsigned int*)(ldst), 16, 0, 0)

#define VWAIT12 asm volatile("s_waitcnt vmcnt(12)" ::: "memory")
#define BAR     __builtin_amdgcn_s_barrier()
#define SCB     __builtin_amdgcn_sched_barrier(0)

template <int EPI, int PERB>
__global__ __launch_bounds__(256, 2)
void mconv_k(const ushort* __restrict__ inH, const ushort* __restrict__ inL,
             const ushort* __restrict__ wimg, const float* __restrict__ aux,
             const ushort* __restrict__ rH, const ushort* __restrict__ rL,
             ushort* __restrict__ oH, ushort* __restrict__ oL,
             float* __restrict__ onchw, const ushort* __restrict__ zb) {
    __shared__ __align__(16) char lds[43520];    // 2 x 21760 B input chunk buffers
    const int tid = threadIdx.x;
    const int orig = blockIdx.x;
    const int blk = (orig & 7) * 256 + (orig >> 3);   // XCD swizzle (2048 % 8 == 0)
    const int b = blk >> 8, t8 = blk & 255;
    const int y0 = (t8 >> 3) << 3, x0 = (t8 & 7) << 5;
    const int wv = tid >> 6, l = tid & 63, ln = l & 31, lh = l >> 5;

    const ushort* wsrc = wimg + (PERB ? (size_t)b * 73728 : 0);
    const int aoff = ln * 16 + lh * 8;           // ushort offset, m=0; m=1: +512; L: +1024

    // per-lane DMA source addresses (interior rounds 0..4 + halo round)
    const ushort* iaddr[5];
    #pragma unroll
    for (int r = 0; r < 5; ++r) {
        int G = r * 256 + tid;
        int p = G >> 2, sp = G & 3;
        int k = (sp - (p >> 1)) & 3;             // inverse of read permutation
        int pl_ = k >> 1, kh = k & 1;
        int trow = p >> 5, px = p & 31;
        int gy = y0 - 1 + trow;
        const ushort* base = pl_ ? inL : inH;
        iaddr[r] = ((unsigned)gy < 256u)
            ? base + ((((size_t)b << 16) + ((size_t)gy << 8) + (x0 + px)) << 6) + kh * 8
            : zb;
    }
    const ushort* haddr = zb;
    if (tid < 80) {
        int q = tid >> 2, sp = tid & 3;
        int k = (sp - (q >> 1)) & 3;
        int pl_ = k >> 1, kh = k & 1;
        int side = q / 10, trow = q % 10;
        int gy = y0 - 1 + trow;
        int gx = side ? x0 + 32 : x0 - 1;
        const ushort* base = pl_ ? inL : inH;
        if (((unsigned)gy < 256u) & ((unsigned)gx < 256u))
            haddr = base + ((((size_t)b << 16) + ((size_t)gy << 8) + gx) << 6) + kh * 8;
    }

    f32x16 acc[2][2];
    #pragma unroll
    for (int m = 0; m < 2; ++m)
        #pragma unroll
        for (int j = 0; j < 2; ++j) acc[m][j] = (f32x16)(0.0f);

    short8 A0H[3][2], A0L[3][2], A1H[3][2], A1L[3][2];

#define ISSUE_DMA(cc, bsel) { \
    char* bufb_ = lds + (bsel) * 21760; \
    _Pragma("unroll") for (int r_ = 0; r_ < 5; ++r_) \
        GLDS(iaddr[r_] + (cc) * 16, bufb_ + r_ * 4096 + (tid & 192) * 16); \
    if (tid < 80) GLDS(haddr + (cc) * 16, bufb_ + 20480 + (tid & 192) * 16); }

#define LOADA(BNK, PH) { \
    _Pragma("unroll") for (int dy_ = 0; dy_ < 3; ++dy_) { \
        const ushort* ab_ = wsrc + (size_t)((PH) * 3 + dy_) * 2048 + aoff; \
        BNK##H[dy_][0] = *(const short8*)ab_; \
        BNK##H[dy_][1] = *(const short8*)(ab_ + 512); \
        BNK##L[dy_][0] = *(const short8*)(ab_ + 1024); \
        BNK##L[dy_][1] = *(const short8*)(ab_ + 1536); \
    } }

#define PHASE(I, C, DX, CURB, NXTB) { \
    if ((I) < 11) LOADA(NXTB, (I) + 1); \
    if ((DX) == 0 && (C) < 3) ISSUE_DMA((C) + 1, ((C) + 1) & 1); \
    const char* bufb_ = lds + ((C) & 1) * 21760; \
    short8 bH[4], bL[4]; \
    _Pragma("unroll") for (int r_ = 0; r_ < 4; ++r_) { \
        const int trow_ = 2 * wv + r_; \
        const int px_ = ln + (DX) - 1; \
        const int p_ = trow_ * 32 + px_; \
        const int q_ = ((px_ > 31) ? 10 : 0) + trow_; \
        const bool hal_ = (px_ < 0) | (px_ > 31); \
        const int gH_ = hal_ ? (1280 + 4 * q_ + ((lh + (q_ >> 1)) & 3)) \
                             : (4 * p_ + ((lh + (p_ >> 1)) & 3)); \
        const int gL_ = hal_ ? (1280 + 4 * q_ + ((2 + lh + (q_ >> 1)) & 3)) \
                             : (4 * p_ + ((2 + lh + (p_ >> 1)) & 3)); \
        bH[r_] = *(const short8*)(bufb_ + gH_ * 16); \
        bL[r_] = *(const short8*)(bufb_ + gL_ * 16); \
    } \
    __builtin_amdgcn_s_setprio(1); \
    _Pragma("unroll") for (int dy_ = 0; dy_ < 3; ++dy_) \
        _Pragma("unroll") for (int j_ = 0; j_ < 2; ++j_) { \
            const int r_ = j_ + dy_; \
            acc[0][j_] = __builtin_amdgcn_mfma_f32_32x32x16_bf16(CURB##H[dy_][0], bH[r_], acc[0][j_], 0, 0, 0); \
            acc[0][j_] = __builtin_amdgcn_mfma_f32_32x32x16_bf16(CURB##H[dy_][0], bL[r_], acc[0][j_], 0, 0, 0); \
            acc[0][j_] = __builtin_amdgcn_mfma_f32_32x32x16_bf16(CURB##L[dy_][0], bH[r_], acc[0][j_], 0, 0, 0); \
            acc[1][j_] = __builtin_amdgcn_mfma_f32_32x32x16_bf16(CURB##H[dy_][1], bH[r_], acc[1][j_], 0, 0, 0); \
            acc[1][j_] = __builtin_amdgcn_mfma_f32_32x32x16_bf16(CURB##H[dy_][1], bL[r_], acc[1][j_], 0, 0, 0); \
            acc[1][j_] = __builtin_amdgcn_mfma_f32_32x32x16_bf16(CURB##L[dy_][1], bH[r_], acc[1][j_], 0, 0, 0); \
        } \
    __builtin_amdgcn_s_setprio(0); \
    if ((DX) == 2 && (C) < 3) { SCB; VWAIT12; BAR; SCB; } }

    // prologue: DMA chunk 0, A for phase 0; counted drain keeps A in flight
    ISSUE_DMA(0, 0);
    LOADA(A0, 0);
    SCB; VWAIT12; BAR; SCB;

    PHASE(0, 0, 0, A0, A1);  PHASE(1, 0, 1, A1, A0);  PHASE(2, 0, 2, A0, A1);
    PHASE(3, 1, 0, A1, A0);  PHASE(4, 1, 1, A0, A1);  PHASE(5, 1, 2, A1, A0);
    PHASE(6, 2, 0, A0, A1);  PHASE(7, 2, 1, A1, A0);  PHASE(8, 2, 2, A0, A1);
    PHASE(9, 3, 0, A1, A0);  PHASE(10, 3, 1, A0, A1); PHASE(11, 3, 2, A1, A0);

#undef ISSUE_DMA
#undef LOADA
#undef PHASE

    // ---- epilogue: C/D col = ln(px), row = 8q + 4lh + (0..3), +32m ----
    #pragma unroll
    for (int m = 0; m < 2; ++m)
        #pragma unroll
        for (int j = 0; j < 2; ++j) {
            const int yo = y0 + 2 * wv + j;
            const size_t pix = ((size_t)b << 16) + ((size_t)yo << 8) + x0 + ln;
            #pragma unroll
            for (int q = 0; q < 4; ++q) {
                const int co0 = m * 32 + 8 * q + 4 * lh;
                float v0 = acc[m][j][4 * q + 0], v1 = acc[m][j][4 * q + 1];
                float v2 = acc[m][j][4 * q + 2], v3 = acc[m][j][4 * q + 3];
                if (EPI == 0) {
                    float4 al = *(const float4*)(aux + co0);
                    v0 = v0 > 0.f ? v0 : al.x * v0;
                    v1 = v1 > 0.f ? v1 : al.y * v1;
                    v2 = v2 > 0.f ? v2 : al.z * v2;
                    v3 = v3 > 0.f ? v3 : al.w * v3;
                } else if (EPI == 1) {
                    const size_t ca = pix * 64 + co0;
                    ushort4 rh = *(const ushort4*)(rH + ca);
                    ushort4 rl = *(const ushort4*)(rL + ca);
                    v0 += b2f(rh.x) + b2f(rl.x);
                    v1 += b2f(rh.y) + b2f(rl.y);
                    v2 += b2f(rh.z) + b2f(rl.z);
                    v3 += b2f(rh.w) + b2f(rl.w);
                } else {
                    float4 bi = *(const float4*)(aux + co0);
                    float ob;
                    ob = v0 + bi.x; v0 = (ob > 0.f ? ob : 0.2f * ob) * SQRT2;
                    ob = v1 + bi.y; v1 = (ob > 0.f ? ob : 0.2f * ob) * SQRT2;
                    ob = v2 + bi.z; v2 = (ob > 0.f ? ob : 0.2f * ob) * SQRT2;
                    ob = v3 + bi.w; v3 = (ob > 0.f ? ob : 0.2f * ob) * SQRT2;
                }
                if (EPI == 2) {
                    const size_t sp = ((size_t)yo << 8) + x0 + ln;
                    onchw[(((size_t)(b * 64 + co0 + 0)) << 16) + sp] = v0;
                    onchw[(((size_t)(b * 64 + co0 + 1)) << 16) + sp] = v1;
                    onchw[(((size_t)(b * 64 + co0 + 2)) << 16) + sp] = v2;
                    onchw[(((size_t)(b * 64 + co0 + 3)) << 16) + sp] = v3;
                } else {
                    ushort4 h4, l4;
                    splitv(v0, h4.x, l4.x); splitv(v1, h4.y, l4.y);
                    splitv(v2, h4.z, l4.z); splitv(v3, h4.w, l4.w);
                    const size_t ca = pix * 64 + co0;
                    *(ushort4*)(oH + ca) = h4;
                    *(ushort4*)(oL + ca) = l4;
                }
            }
        }
}

// ---------------------------------------------------------------------------
// Host launch
// ---------------------------------------------------------------------------
extern "C" void kernel_launch(void* const* d_in, const int* in_sizes, int n_in,
                              void* d_out, int out_size, void* d_ws, size_t ws_size,
                              hipStream_t stream) {
    const float* x       = (const float*)d_in[0];
    const float* style   = (const float*)d_in[1];
    const float* w1a     = (const float*)d_in[2];
    const float* alpha1  = (const float*)d_in[3];
    const float* w1b     = (const float*)d_in[4];
    const float* w2a     = (const float*)d_in[5];
    const float* alpha2  = (const float*)d_in[6];
    const float* w2b     = (const float*)d_in[7];
    const float* mod_w   = (const float*)d_in[8];
    const float* mod_b   = (const float*)d_in[9];
    const float* conv_w  = (const float*)d_in[10];
    const float* fused_b = (const float*)d_in[11];
    float* out = (float*)d_out;

    char* ws = (char*)d_ws;
    float*  zbf   = (float*)ws;                  // 256 B zero buffer
    float*  sbuf  = (float*)(ws + 256);          // 512 f
    float*  demod = (float*)(ws + 2304);         // 512 f
    ushort* wfix  = (ushort*)(ws + 4352);        // 4 x 147456 B images
    ushort* wmod  = (ushort*)(ws + 594176);      // 8 x 147456 B
    char*   pl    = ws + 1774080;
    const size_t PAIRB = 134217728ull;           // one H+L plane pair (bytes)
    const size_t PLEL  = 33554432ull;            // elements per plane

    ushort* XPH = (ushort*)pl;             ushort* XPL = XPH + PLEL;
    ushort* PBH = (ushort*)(pl + PAIRB);   ushort* PBL = PBH + PLEL;
    ushort *PAH, *PAL;
    if (ws_size >= 1774080ull + 3 * PAIRB) {
        PAH = (ushort*)(pl + 2 * PAIRB); PAL = PAH + PLEL;
    } else {
        PAH = (ushort*)d_out; PAL = PAH + PLEL;  // d_out hosts PA; rewritten by c5
    }
    const ushort* zb = (const ushort*)zbf;

    // --- prep ---
    hipLaunchKernelGGL(zero_k, dim3(1), dim3(64), 0, stream, zbf);
    hipLaunchKernelGGL(tocl_k, dim3(BB * 1024), dim3(256), 0, stream, x, XPH, XPL);
    hipLaunchKernelGGL(packw_k, dim3(288), dim3(256), 0, stream, w1a, wfix + 0 * 73728);
    hipLaunchKernelGGL(packw_k, dim3(288), dim3(256), 0, stream, w1b, wfix + 1 * 73728);
    hipLaunchKernelGGL(packw_k, dim3(288), dim3(256), 0, stream, w2a, wfix + 2 * 73728);
    hipLaunchKernelGGL(packw_k, dim3(288), dim3(256), 0, stream, w2b, wfix + 3 * 73728);
    hipLaunchKernelGGL(style_s_k, dim3(1), dim3(512), 0, stream, style, mod_w, mod_b, sbuf);
    hipLaunchKernelGGL(demod_k, dim3(1), dim3(512), 0, stream, conv_w, sbuf, demod);
    hipLaunchKernelGGL(packmod_k, dim3(2304), dim3(256), 0, stream, conv_w, sbuf, demod, wmod);

    // --- conv chain ---
    const dim3 cgrid(2048), cblk(256);
    // c1: t1 = prelu(conv(x, w1a))           XP -> PA
    hipLaunchKernelGGL((mconv_k<0, 0>), cgrid, cblk, 0, stream,
        XPH, XPL, wfix + 0 * 73728, alpha1, (const ushort*)nullptr, (const ushort*)nullptr,
        PAH, PAL, (float*)nullptr, zb);
    // c2: h1 = x + conv(t1, w1b)             PA -> PB  (resid XP)
    hipLaunchKernelGGL((mconv_k<1, 0>), cgrid, cblk, 0, stream,
        PAH, PAL, wfix + 1 * 73728, (const float*)nullptr, XPH, XPL,
        PBH, PBL, (float*)nullptr, zb);
    // c3: t2 = prelu(conv(h1, w2a))          PB -> PA
    hipLaunchKernelGGL((mconv_k<0, 0>), cgrid, cblk, 0, stream,
        PBH, PBL, wfix + 2 * 73728, alpha2, (const ushort*)nullptr, (const ushort*)nullptr,
        PAH, PAL, (float*)nullptr, zb);
    // c4: h2 = h1 + conv(t2, w2b)            PA -> PB  (resid PB, in-place same-index)
    hipLaunchKernelGGL((mconv_k<1, 0>), cgrid, cblk, 0, stream,
        PAH, PAL, wfix + 3 * 73728, (const float*)nullptr, PBH, PBL,
        PBH, PBL, (float*)nullptr, zb);
    // c5: out = fused_lrelu(modconv(h2)+b)   PB -> out (NCHW fp32)
    hipLaunchKernelGGL((mconv_k<2, 1>), cgrid, cblk, 0, stream,
        PBH, PBL, wmod, fused_b, (const ushort*)nullptr, (const ushort*)nullptr,
        (ushort*)nullptr, (ushort*)nullptr, out, zb);
}

// Round 8
// 963.962 us; speedup vs baseline: 1.1580x; 1.1580x over previous
//
#include <hip/hip_runtime.h>
#include <hip/hip_bf16.h>
#include <math.h>

#define BB 8
#define SS 512
#define LIN_SCALE 0.044194173824159216f   // 1/sqrt(512)
#define CONV_SCALE 0.041666666666666664f  // 1/sqrt(64*9)
#define SQRT2 1.4142135623730951f

typedef __attribute__((ext_vector_type(8))) short short8;
typedef __attribute__((ext_vector_type(16))) float f32x16;

__device__ __forceinline__ ushort bf16h(float v) {
    unsigned u = __float_as_uint(v);
    return (ushort)((u + 0x7fffu + ((u >> 16) & 1u)) >> 16);
}
__device__ __forceinline__ void splitv(float v, ushort& h, ushort& l) {
    h = bf16h(v);
    l = bf16h(v - __uint_as_float((unsigned)h << 16));
}
__device__ __forceinline__ float b2f(ushort u) { return __uint_as_float((unsigned)u << 16); }

// ---------------------------------------------------------------------------
// Global chunked-CL input format: region (b, cc) = 65536 pixels; per pixel a
// 64B granule-quad: ushorts [0..7]=H ch cc*16+0..7, [8..15]=H +8,
// [16..23]=L +0, [24..31]=L +8.  Total 8*4*65536*32 ush = 134,217,728 B.
// ---------------------------------------------------------------------------

__global__ void zero_k(float* z) { z[threadIdx.x] = 0.f; }   // 64 thr -> 256 B

// NCHW fp32 -> chunked-CL bf16 hi/lo
__global__ __launch_bounds__(256) void tocl_k(const float* __restrict__ x,
                                              ushort* __restrict__ oCL) {
    __shared__ float tile[64][65];
    const int blk = blockIdx.x;                  // 8*256*4
    const int b = blk >> 10, rem = blk & 1023;
    const int y = rem >> 2, x0 = (rem & 3) << 6;
    const int tid = threadIdx.x, lane = tid & 63, g = tid >> 6;
    const float* xb = x + ((size_t)b << 22) + (y << 8) + x0;
    #pragma unroll
    for (int i = 0; i < 16; ++i) {
        int c = i * 4 + g;
        tile[c][lane] = xb[((size_t)c << 16) + lane];
    }
    __syncthreads();
    const int cc = tid >> 6, xx = tid & 63;
    ushort hh[16], ll[16];
    #pragma unroll
    for (int t = 0; t < 16; ++t) splitv(tile[cc * 16 + t][xx], hh[t], ll[t]);
    uint w[16];
    #pragma unroll
    for (int i = 0; i < 8; ++i) {
        w[i]     = (uint)hh[2 * i] | ((uint)hh[2 * i + 1] << 16);
        w[8 + i] = (uint)ll[2 * i] | ((uint)ll[2 * i + 1] << 16);
    }
    ushort* dst = oCL + ((((size_t)(b * 4 + cc)) << 16) + (y << 8) + x0 + xx) * 32;
    *(uint4*)(dst +  0) = make_uint4(w[0], w[1], w[2], w[3]);
    *(uint4*)(dst +  8) = make_uint4(w[4], w[5], w[6], w[7]);
    *(uint4*)(dst + 16) = make_uint4(w[8], w[9], w[10], w[11]);
    *(uint4*)(dst + 24) = make_uint4(w[12], w[13], w[14], w[15]);
}

// Weight image == LDS image. ushort i: cc = i/18432; j = i%18432; e = j&7;
// slot s = j>>3; F = s>>6; u = s&63; ln = u>>1; lh = u&1;
// m = F&1; pl = (F>>1)&1; td = F>>2; dx = td/3; dy = td%3;
// co = m*32+ln; ci = cc*16+lh*8+e; src tap = dy*3+dx.
__device__ __forceinline__ int wsrc_idx(int i, int& pl) {
    int e = i & 7;
    int j = (i % 18432) >> 3;
    int cc = i / 18432;
    int F = j >> 6, u = j & 63;
    int ln_ = u >> 1, lh_ = u & 1;
    int m = F & 1; pl = (F >> 1) & 1;
    int td = F >> 2;
    int dx = td / 3, dy = td - 3 * dx;
    int co = m * 32 + ln_;
    int ci = cc * 16 + lh_ * 8 + e;
    return (co * 64 + ci) * 9 + dy * 3 + dx;
}

__global__ void packw_k(const float* __restrict__ w, ushort* __restrict__ img) {
    int i = blockIdx.x * 256 + threadIdx.x;      // 73728
    if (i >= 73728) return;
    int pl; int src = wsrc_idx(i, pl);
    ushort h, l; splitv(w[src], h, l);
    img[i] = pl ? l : h;
}

__global__ void style_s_k(const float* __restrict__ style, const float* __restrict__ mod_w,
                          const float* __restrict__ mod_b, float* __restrict__ sbuf) {
    int tid = threadIdx.x;                       // 512
    int b = tid >> 6, cin = tid & 63;
    float acc = 0.f;
    for (int j = 0; j < SS; ++j) acc += style[b * SS + j] * mod_w[cin * SS + j];
    sbuf[b * 64 + cin] = acc * LIN_SCALE + mod_b[cin];
}

__global__ void demod_k(const float* __restrict__ conv_w, const float* __restrict__ sbuf,
                        float* __restrict__ demod) {
    int tid = threadIdx.x;                       // 512
    int b = tid >> 6, cout = tid & 63;
    float sum = 0.f;
    for (int cin = 0; cin < 64; ++cin) {
        float m = CONV_SCALE * sbuf[b * 64 + cin];
        const float* wp = conv_w + (cout * 64 + cin) * 9;
        #pragma unroll
        for (int k = 0; k < 9; ++k) { float v = wp[k] * m; sum += v * v; }
    }
    demod[b * 64 + cout] = 1.0f / sqrtf(sum + 1e-8f);
}

__global__ void packmod_k(const float* __restrict__ conv_w, const float* __restrict__ sbuf,
                          const float* __restrict__ demod, ushort* __restrict__ img) {
    int i = blockIdx.x * 256 + threadIdx.x;      // 589824
    if (i >= 589824) return;
    int b = i / 73728, ii = i % 73728;
    int pl; int src = wsrc_idx(ii, pl);
    int co = src / 576; int ci = (src / 9) % 64;
    float v = CONV_SCALE * conv_w[src] * sbuf[b * 64 + ci] * demod[b * 64 + co];
    ushort h, l; splitv(v, h, l);
    img[i] = pl ? l : h;
}

// ---------------------------------------------------------------------------
// MFMA conv: 3x3 C64->C64 SAME. Chunked-CL bf16 H/L input.
// Block 256 thr = 4 waves; tile 16 rows x 32 px; 64 couts. Wave wv: output
// rows 4wv..4wv+3 (4 N-frags) x 2 M-frags. K chunked 16 cins (4 chunks).
// LDS: input dbuf 2x40960 (18 rows x 34 px x 4 granules, slot perm
// sp=(k+(p>>1))&3) + weight dbuf 2x36864 (lane-linear). 155648 B, 1 blk/CU.
// One vmcnt(0)+barrier per chunk; DMA for c+1 issued at chunk-c start.
// EPI: 0 = PReLU->CL, 1 = +resid(CL)->CL, 2 = fusedLReLU->NCHW fp32.
// ---------------------------------------------------------------------------
#define GLDS(gsrc, ldst) __builtin_amdgcn_global_load_lds( \
    (const __attribute__((address_space(1))) unsigned int*)(gsrc), \
    (__attribute__((address_space(3))) unsigned int*)(ldst), 16, 0, 0)

#define VWAIT0 asm volatile("s_waitcnt vmcnt(0)" ::: "memory")
#define BAR    __builtin_amdgcn_s_barrier()
#define SCB    __builtin_amdgcn_sched_barrier(0)
#define MFMA32(a, bb, c) __builtin_amdgcn_mfma_f32_32x32x16_bf16(a, bb, c, 0, 0, 0)

template <int EPI, int PERB>
__global__ __launch_bounds__(256, 1)
void mconv_k(const ushort* __restrict__ inCL, const ushort* __restrict__ wimg,
             const float* __restrict__ aux, const ushort* __restrict__ rCL,
             ushort* __restrict__ oCL, float* __restrict__ onchw,
             const ushort* __restrict__ zb) {
    __shared__ __align__(16) char lds[155648];   // ibuf 2x40960 | wbuf 2x36864
    const int tid = threadIdx.x;
    const int orig = blockIdx.x;
    const int blk = (orig & 7) * 128 + (orig >> 3);   // XCD swizzle (1024 % 8 == 0)
    const int b = blk >> 7, t7 = blk & 127;
    const int y0 = (t7 >> 3) << 4, x0 = (t7 & 7) << 5;
    const int wv = tid >> 6, l = tid & 63, ln = l & 31, lh = l >> 5;

    const ushort* wsrc = wimg + (PERB ? (size_t)b * 73728 : 0);

    f32x16 acc[2][4];
    #pragma unroll
    for (int m = 0; m < 2; ++m)
        #pragma unroll
        for (int j = 0; j < 4; ++j) acc[m][j] = (f32x16)(0.0f);

#define ISSUE_IN(cc, bo) { \
    _Pragma("unroll") for (int r_ = 0; r_ < 10; ++r_) { \
        const int s_ = r_ * 256 + tid; \
        const int p_ = s_ >> 2, sp_ = s_ & 3; \
        const int k_ = (sp_ - (p_ >> 1)) & 3; \
        const int row_ = p_ / 34, u_ = p_ - row_ * 34; \
        const int gy_ = y0 - 1 + row_, gx_ = x0 + u_ - 1; \
        const bool ok_ = ((unsigned)gy_ < 256u) & ((unsigned)gx_ < 256u) & (p_ < 612); \
        const ushort* src_ = ok_ \
            ? inCL + ((((size_t)(b * 4 + (cc))) << 16) + (gy_ << 8) + gx_) * 32 + k_ * 8 \
            : zb; \
        GLDS(src_, lds + (bo) + r_ * 4096 + (tid & 192) * 16); \
    } }

#define ISSUE_W(cc, bo) { \
    const ushort* wsB_ = wsrc + (cc) * 18432; \
    _Pragma("unroll") for (int r_ = 0; r_ < 9; ++r_) \
        GLDS(wsB_ + r_ * 2048 + tid * 8, lds + (bo) + r_ * 4096 + (tid & 192) * 16); }

#define PHASE(C, DX) { \
    const char* ib_ = lds + ((C) & 1) * 40960; \
    const char* wb_ = lds + 81920 + ((C) & 1) * 36864; \
    short8 bH_[6], bL_[6]; \
    _Pragma("unroll") for (int r_ = 0; r_ < 6; ++r_) { \
        const int p_ = (4 * wv + r_) * 34 + ln + (DX); \
        const int gH_ = 4 * p_ + ((lh + (p_ >> 1)) & 3); \
        const int gL_ = 4 * p_ + ((2 + lh + (p_ >> 1)) & 3); \
        bH_[r_] = *(const short8*)(ib_ + gH_ * 16); \
        bL_[r_] = *(const short8*)(ib_ + gL_ * 16); \
    } \
    _Pragma("unroll") for (int dy_ = 0; dy_ < 3; ++dy_) { \
        const char* wa_ = wb_ + ((DX) * 3 + dy_) * 4096 + (ln * 2 + lh) * 16; \
        const short8 aH0_ = *(const short8*)(wa_); \
        const short8 aH1_ = *(const short8*)(wa_ + 1024); \
        const short8 aL0_ = *(const short8*)(wa_ + 2048); \
        const short8 aL1_ = *(const short8*)(wa_ + 3072); \
        _Pragma("unroll") for (int j_ = 0; j_ < 4; ++j_) { \
            const int r_ = j_ + dy_; \
            acc[0][j_] = MFMA32(aH0_, bH_[r_], acc[0][j_]); \
            acc[0][j_] = MFMA32(aH0_, bL_[r_], acc[0][j_]); \
            acc[0][j_] = MFMA32(aL0_, bH_[r_], acc[0][j_]); \
            acc[1][j_] = MFMA32(aH1_, bH_[r_], acc[1][j_]); \
            acc[1][j_] = MFMA32(aH1_, bL_[r_], acc[1][j_]); \
            acc[1][j_] = MFMA32(aL1_, bH_[r_], acc[1][j_]); \
        } \
    } }

#define CHUNK(C) { \
    if ((C) < 3) { ISSUE_IN((C) + 1, (((C) + 1) & 1) * 40960); \
                   ISSUE_W((C) + 1, 81920 + (((C) + 1) & 1) * 36864); } \
    PHASE(C, 0); PHASE(C, 1); PHASE(C, 2); \
    if ((C) < 3) { SCB; VWAIT0; BAR; SCB; } }

    // prologue
    ISSUE_IN(0, 0);
    ISSUE_W(0, 81920);
    SCB; VWAIT0; BAR; SCB;

    CHUNK(0); CHUNK(1); CHUNK(2); CHUNK(3);

#undef ISSUE_IN
#undef ISSUE_W
#undef PHASE
#undef CHUNK

    // ---- epilogue: C/D col = ln(px), row = 8q + 4lh + (0..3), +32m ----
    #pragma unroll
    for (int m = 0; m < 2; ++m)
        #pragma unroll
        for (int j = 0; j < 4; ++j) {
            const int yo = y0 + 4 * wv + j;
            const int pixel = (yo << 8) + x0 + ln;
            #pragma unroll
            for (int q = 0; q < 4; ++q) {
                const int co0 = m * 32 + 8 * q + 4 * lh;
                float v0 = acc[m][j][4 * q + 0], v1 = acc[m][j][4 * q + 1];
                float v2 = acc[m][j][4 * q + 2], v3 = acc[m][j][4 * q + 3];
                const int cc_o = co0 >> 4, ch = co0 & 15;
                const size_t gbase = ((((size_t)(b * 4 + cc_o)) << 16) + pixel) * 32 + ch;
                if (EPI == 0) {
                    float4 al = *(const float4*)(aux + co0);
                    v0 = v0 > 0.f ? v0 : al.x * v0;
                    v1 = v1 > 0.f ? v1 : al.y * v1;
                    v2 = v2 > 0.f ? v2 : al.z * v2;
                    v3 = v3 > 0.f ? v3 : al.w * v3;
                } else if (EPI == 1) {
                    ushort4 rh = *(const ushort4*)(rCL + gbase);
                    ushort4 rl = *(const ushort4*)(rCL + gbase + 16);
                    v0 += b2f(rh.x) + b2f(rl.x);
                    v1 += b2f(rh.y) + b2f(rl.y);
                    v2 += b2f(rh.z) + b2f(rl.z);
                    v3 += b2f(rh.w) + b2f(rl.w);
                } else {
                    float4 bi = *(const float4*)(aux + co0);
                    float ob;
                    ob = v0 + bi.x; v0 = (ob > 0.f ? ob : 0.2f * ob) * SQRT2;
                    ob = v1 + bi.y; v1 = (ob > 0.f ? ob : 0.2f * ob) * SQRT2;
                    ob = v2 + bi.z; v2 = (ob > 0.f ? ob : 0.2f * ob) * SQRT2;
                    ob = v3 + bi.w; v3 = (ob > 0.f ? ob : 0.2f * ob) * SQRT2;
                }
                if (EPI == 2) {
                    const size_t sp = (size_t)pixel;
                    onchw[(((size_t)(b * 64 + co0 + 0)) << 16) + sp] = v0;
                    onchw[(((size_t)(b * 64 + co0 + 1)) << 16) + sp] = v1;
                    onchw[(((size_t)(b * 64 + co0 + 2)) << 16) + sp] = v2;
                    onchw[(((size_t)(b * 64 + co0 + 3)) << 16) + sp] = v3;
                } else {
                    ushort4 h4, l4;
                    splitv(v0, h4.x, l4.x); splitv(v1, h4.y, l4.y);
                    splitv(v2, h4.z, l4.z); splitv(v3, h4.w, l4.w);
                    *(ushort4*)(oCL + gbase) = h4;
                    *(ushort4*)(oCL + gbase + 16) = l4;
                }
            }
        }
}

// ---------------------------------------------------------------------------
// Host launch
// ---------------------------------------------------------------------------
extern "C" void kernel_launch(void* const* d_in, const int* in_sizes, int n_in,
                              void* d_out, int out_size, void* d_ws, size_t ws_size,
                              hipStream_t stream) {
    const float* x       = (const float*)d_in[0];
    const float* style   = (const float*)d_in[1];
    const float* w1a     = (const float*)d_in[2];
    const float* alpha1  = (const float*)d_in[3];
    const float* w1b     = (const float*)d_in[4];
    const float* w2a     = (const float*)d_in[5];
    const float* alpha2  = (const float*)d_in[6];
    const float* w2b     = (const float*)d_in[7];
    const float* mod_w   = (const float*)d_in[8];
    const float* mod_b   = (const float*)d_in[9];
    const float* conv_w  = (const float*)d_in[10];
    const float* fused_b = (const float*)d_in[11];
    float* out = (float*)d_out;

    char* ws = (char*)d_ws;
    float*  zbf   = (float*)ws;                  // 256 B zero buffer
    float*  sbuf  = (float*)(ws + 256);          // 512 f
    float*  demod = (float*)(ws + 2304);         // 512 f
    ushort* wfix  = (ushort*)(ws + 4352);        // 4 x 147456 B images
    ushort* wmod  = (ushort*)(ws + 594176);      // 8 x 147456 B
    char*   pl    = ws + 1774080;
    const size_t PAIRB = 134217728ull;           // one chunked-CL buffer (bytes)

    ushort* XP = (ushort*)pl;
    ushort* PB = (ushort*)(pl + PAIRB);
    ushort* PA;
    if (ws_size >= 1774080ull + 3 * PAIRB) PA = (ushort*)(pl + 2 * PAIRB);
    else                                   PA = (ushort*)d_out;  // rewritten by c5
    const ushort* zb = (const ushort*)zbf;

    // --- prep ---
    hipLaunchKernelGGL(zero_k, dim3(1), dim3(64), 0, stream, zbf);
    hipLaunchKernelGGL(tocl_k, dim3(BB * 1024), dim3(256), 0, stream, x, XP);
    hipLaunchKernelGGL(packw_k, dim3(288), dim3(256), 0, stream, w1a, wfix + 0 * 73728);
    hipLaunchKernelGGL(packw_k, dim3(288), dim3(256), 0, stream, w1b, wfix + 1 * 73728);
    hipLaunchKernelGGL(packw_k, dim3(288), dim3(256), 0, stream, w2a, wfix + 2 * 73728);
    hipLaunchKernelGGL(packw_k, dim3(288), dim3(256), 0, stream, w2b, wfix + 3 * 73728);
    hipLaunchKernelGGL(style_s_k, dim3(1), dim3(512), 0, stream, style, mod_w, mod_b, sbuf);
    hipLaunchKernelGGL(demod_k, dim3(1), dim3(512), 0, stream, conv_w, sbuf, demod);
    hipLaunchKernelGGL(packmod_k, dim3(2304), dim3(256), 0, stream, conv_w, sbuf, demod, wmod);

    // --- conv chain ---
    const dim3 cgrid(1024), cblk(256);
    // c1: t1 = prelu(conv(x, w1a))           XP -> PA
    hipLaunchKernelGGL((mconv_k<0, 0>), cgrid, cblk, 0, stream,
        XP, wfix + 0 * 73728, alpha1, (const ushort*)nullptr, PA, (float*)nullptr, zb);
    // c2: h1 = x + conv(t1, w1b)             PA -> PB  (resid XP)
    hipLaunchKernelGGL((mconv_k<1, 0>), cgrid, cblk, 0, stream,
        PA, wfix + 1 * 73728, (const float*)nullptr, XP, PB, (float*)nullptr, zb);
    // c3: t2 = prelu(conv(h1, w2a))          PB -> PA
    hipLaunchKernelGGL((mconv_k<0, 0>), cgrid, cblk, 0, stream,
        PB, wfix + 2 * 73728, alpha2, (const ushort*)nullptr, PA, (float*)nullptr, zb);
    // c4: h2 = h1 + conv(t2, w2b)            PA -> PB  (resid PB, same-index in-place)
    hipLaunchKernelGGL((mconv_k<1, 0>), cgrid, cblk, 0, stream,
        PA, wfix + 3 * 73728, (const float*)nullptr, PB, PB, (float*)nullptr, zb);
    // c5: out = fused_lrelu(modconv(h2)+b)   PB -> out (NCHW fp32)
    hipLaunchKernelGGL((mconv_k<2, 1>), cgrid, cblk, 0, stream,
        PB, wmod, fused_b, (const ushort*)nullptr, (ushort*)nullptr, out, zb);
}

// Round 9
// 950.994 us; speedup vs baseline: 1.1738x; 1.0136x over previous
//
#include <hip/hip_runtime.h>
#include <hip/hip_bf16.h>
#include <math.h>

#define BB 8
#define SS 512
#define LIN_SCALE 0.044194173824159216f   // 1/sqrt(512)
#define CONV_SCALE 0.041666666666666664f  // 1/sqrt(64*9)
#define SQRT2 1.4142135623730951f

typedef __attribute__((ext_vector_type(8))) short short8;
typedef __attribute__((ext_vector_type(16))) float f32x16;

__device__ __forceinline__ ushort bf16h(float v) {
    unsigned u = __float_as_uint(v);
    return (ushort)((u + 0x7fffu + ((u >> 16) & 1u)) >> 16);
}
__device__ __forceinline__ void splitv(float v, ushort& h, ushort& l) {
    h = bf16h(v);
    l = bf16h(v - __uint_as_float((unsigned)h << 16));
}
__device__ __forceinline__ float b2f(ushort u) { return __uint_as_float((unsigned)u << 16); }

// ---------------------------------------------------------------------------
// Global chunked-CL format (proven in R8): region (b, cc) = 65536 pixels; per
// pixel a 64B granule-quad: u16 [0..7]=H c0..7, [8..15]=H c8..15,
// [16..23]=L c0..7, [24..31]=L c8..15.
// ---------------------------------------------------------------------------

__global__ void zero_k(float* z) { z[threadIdx.x] = 0.f; }   // 64 thr -> 256 B

// NCHW fp32 -> chunked-CL bf16 hi/lo (proven in R8)
__global__ __launch_bounds__(256) void tocl_k(const float* __restrict__ x,
                                              ushort* __restrict__ oCL) {
    __shared__ float tile[64][65];
    const int blk = blockIdx.x;                  // 8*256*4
    const int b = blk >> 10, rem = blk & 1023;
    const int y = rem >> 2, x0 = (rem & 3) << 6;
    const int tid = threadIdx.x, lane = tid & 63, g = tid >> 6;
    const float* xb = x + ((size_t)b << 22) + (y << 8) + x0;
    #pragma unroll
    for (int i = 0; i < 16; ++i) {
        int c = i * 4 + g;
        tile[c][lane] = xb[((size_t)c << 16) + lane];
    }
    __syncthreads();
    const int cc = tid >> 6, xx = tid & 63;
    ushort hh[16], ll[16];
    #pragma unroll
    for (int t = 0; t < 16; ++t) splitv(tile[cc * 16 + t][xx], hh[t], ll[t]);
    uint w[16];
    #pragma unroll
    for (int i = 0; i < 8; ++i) {
        w[i]     = (uint)hh[2 * i] | ((uint)hh[2 * i + 1] << 16);
        w[8 + i] = (uint)ll[2 * i] | ((uint)ll[2 * i + 1] << 16);
    }
    ushort* dst = oCL + ((((size_t)(b * 4 + cc)) << 16) + (y << 8) + x0 + xx) * 32;
    *(uint4*)(dst +  0) = make_uint4(w[0], w[1], w[2], w[3]);
    *(uint4*)(dst +  8) = make_uint4(w[4], w[5], w[6], w[7]);
    *(uint4*)(dst + 16) = make_uint4(w[8], w[9], w[10], w[11]);
    *(uint4*)(dst + 24) = make_uint4(w[12], w[13], w[14], w[15]);
}

// Weight image (proven in R6): i = (((((c*3+dx)*3+dy)*2+pl)*64+co)*2+lh)*8 + e
__device__ __forceinline__ void wdecode(int i, int& c, int& tap, int& co, int& ci, int& pl) {
    int e = i & 7;  int t = i >> 3;
    int lh = t & 1; t >>= 1;
    co = t & 63;    t >>= 6;
    pl = t & 1;     t >>= 1;
    int dy = t % 3; t /= 3;
    int dx = t % 3; t /= 3;
    c = t;
    ci = c * 16 + lh * 8 + e;
    tap = dy * 3 + dx;
}

__global__ void packw_k(const float* __restrict__ w, ushort* __restrict__ img) {
    int i = blockIdx.x * 256 + threadIdx.x;      // 73728
    if (i >= 73728) return;
    int c, tap, co, ci, pl;
    wdecode(i, c, tap, co, ci, pl);
    ushort h, l; splitv(w[(co * 64 + ci) * 9 + tap], h, l);
    img[i] = pl ? l : h;
}

__global__ void style_s_k(const float* __restrict__ style, const float* __restrict__ mod_w,
                          const float* __restrict__ mod_b, float* __restrict__ sbuf) {
    int tid = threadIdx.x;                       // 512
    int b = tid >> 6, cin = tid & 63;
    float acc = 0.f;
    for (int j = 0; j < SS; ++j) acc += style[b * SS + j] * mod_w[cin * SS + j];
    sbuf[b * 64 + cin] = acc * LIN_SCALE + mod_b[cin];
}

__global__ void demod_k(const float* __restrict__ conv_w, const float* __restrict__ sbuf,
                        float* __restrict__ demod) {
    int tid = threadIdx.x;                       // 512
    int b = tid >> 6, cout = tid & 63;
    float sum = 0.f;
    for (int cin = 0; cin < 64; ++cin) {
        float m = CONV_SCALE * sbuf[b * 64 + cin];
        const float* wp = conv_w + (cout * 64 + cin) * 9;
        #pragma unroll
        for (int k = 0; k < 9; ++k) { float v = wp[k] * m; sum += v * v; }
    }
    demod[b * 64 + cout] = 1.0f / sqrtf(sum + 1e-8f);
}

__global__ void packmod_k(const float* __restrict__ conv_w, const float* __restrict__ sbuf,
                          const float* __restrict__ demod, ushort* __restrict__ img) {
    int i = blockIdx.x * 256 + threadIdx.x;      // 589824
    if (i >= 589824) return;
    int b = i / 73728, ii = i % 73728;
    int c, tap, co, ci, pl;
    wdecode(ii, c, tap, co, ci, pl);
    float v = CONV_SCALE * conv_w[(co * 64 + ci) * 9 + tap] * sbuf[b * 64 + ci] * demod[b * 64 + co];
    ushort h, l; splitv(v, h, l);
    img[i] = pl ? l : h;
}

// ---------------------------------------------------------------------------
// MFMA conv: 3x3 C64->C64 SAME. Chunked-CL bf16 H/L input.
// Block 256 thr = 4 waves; tile 8 rows x 32 px; 64 couts. Wave wv: output
// rows 2wv..2wv+1 (2 N) x 2 M frags. K chunked 16 cins (4 chunks x 3 dx).
// A (weights): global->VGPR, double-banked one dx-phase ahead (48x2 VGPR).
// B (input): DMA dbuf LDS 2x21760 B (10 rows x 34 px x 4 granules, slot
// perm sp=(k+(p>>1))&3), coalesced 1KB bursts. Counted vmcnt(12) per chunk
// keeps next-phase A-prefetch in flight. LDS 43520 -> 2 blocks/CU.
// EPI: 0 = PReLU->CL, 1 = +resid(CL)->CL, 2 = fusedLReLU->NCHW fp32.
// ---------------------------------------------------------------------------
#define GLDS(gsrc, ldst) __builtin_amdgcn_global_load_lds( \
    (const __attribute__((address_space(1))) unsigned int*)(gsrc), \
    (__attribute__((address_space(3))) unsigned int*)(ldst), 16, 0, 0)

#define VWAIT12 asm volatile("s_waitcnt vmcnt(12)" ::: "memory")
#define BAR     __builtin_amdgcn_s_barrier()
#define SCB     __builtin_amdgcn_sched_barrier(0)
#define MFMA32(a, bb, c) __builtin_amdgcn_mfma_f32_32x32x16_bf16(a, bb, c, 0, 0, 0)

template <int EPI, int PERB>
__global__ __launch_bounds__(256, 2)
void mconv_k(const ushort* __restrict__ inCL, const ushort* __restrict__ wimg,
             const float* __restrict__ aux, const ushort* __restrict__ rCL,
             ushort* __restrict__ oCL, float* __restrict__ onchw,
             const ushort* __restrict__ zb) {
    __shared__ __align__(16) char lds[43520];    // 2 x 21760 B input chunk buffers
    const int tid = threadIdx.x;
    const int orig = blockIdx.x;
    const int blk = (orig & 7) * 256 + (orig >> 3);   // XCD swizzle (2048 % 8 == 0)
    const int b = blk >> 8, t8 = blk & 255;
    const int y0 = (t8 >> 3) << 3, x0 = (t8 & 7) << 5;
    const int wv = tid >> 6, l = tid & 63, ln = l & 31, lh = l >> 5;

    const ushort* wsrc = wimg + (PERB ? (size_t)b * 73728 : 0);
    const int aoff = ln * 16 + lh * 8;           // ushort offset within tap-block

    f32x16 acc[2][2];
    #pragma unroll
    for (int m = 0; m < 2; ++m)
        #pragma unroll
        for (int j = 0; j < 2; ++j) acc[m][j] = (f32x16)(0.0f);

    short8 A0H[3][2], A0L[3][2], A1H[3][2], A1L[3][2];

#define ISSUE_IN(cc, bo) { \
    _Pragma("unroll") for (int r_ = 0; r_ < 5; ++r_) { \
        const int G_ = r_ * 256 + tid; \
        const int p_ = G_ >> 2, sp_ = G_ & 3; \
        const int k_ = (sp_ - (p_ >> 1)) & 3; \
        const int row_ = p_ / 34, u_ = p_ - row_ * 34; \
        const int gy_ = y0 - 1 + row_, gx_ = x0 + u_ - 1; \
        const bool ok_ = ((unsigned)gy_ < 256u) & ((unsigned)gx_ < 256u); \
        const ushort* src_ = ok_ \
            ? inCL + ((((size_t)(b * 4 + (cc))) << 16) + (gy_ << 8) + gx_) * 32 + k_ * 8 \
            : zb; \
        GLDS(src_, lds + (bo) + r_ * 4096 + (tid & 192) * 16); \
    } \
    { const int G_ = 1280 + tid; \
      const int p_ = G_ >> 2, sp_ = G_ & 3; \
      const int k_ = (sp_ - (p_ >> 1)) & 3; \
      const int row_ = p_ / 34, u_ = p_ - row_ * 34; \
      const int gy_ = y0 - 1 + row_, gx_ = x0 + u_ - 1; \
      const bool ok_ = (tid < 80) & ((unsigned)gy_ < 256u) & ((unsigned)gx_ < 256u); \
      const ushort* src_ = ok_ \
          ? inCL + ((((size_t)(b * 4 + (cc))) << 16) + (gy_ << 8) + gx_) * 32 + k_ * 8 \
          : zb; \
      if (tid < 80) GLDS(src_, lds + (bo) + 20480 + (tid & 192) * 16); } }

#define LOADA(BNK, C, DX) { \
    _Pragma("unroll") for (int dy_ = 0; dy_ < 3; ++dy_) { \
        const ushort* ab_ = wsrc + (size_t)(((C) * 3 + (DX)) * 3 + dy_) * 2048 + aoff; \
        BNK##H[dy_][0] = *(const short8*)ab_; \
        BNK##H[dy_][1] = *(const short8*)(ab_ + 512); \
        BNK##L[dy_][0] = *(const short8*)(ab_ + 1024); \
        BNK##L[dy_][1] = *(const short8*)(ab_ + 1536); \
    } }

#define PHASE(C, DX, CUR) { \
    const char* ib_ = lds + ((C) & 1) * 21760; \
    short8 bH_[4], bL_[4]; \
    _Pragma("unroll") for (int r_ = 0; r_ < 4; ++r_) { \
        const int p_ = (2 * wv + r_) * 34 + ln + (DX); \
        const int gH_ = 4 * p_ + ((lh + (p_ >> 1)) & 3); \
        const int gL_ = 4 * p_ + ((2 + lh + (p_ >> 1)) & 3); \
        bH_[r_] = *(const short8*)(ib_ + gH_ * 16); \
        bL_[r_] = *(const short8*)(ib_ + gL_ * 16); \
    } \
    __builtin_amdgcn_s_setprio(1); \
    _Pragma("unroll") for (int dy_ = 0; dy_ < 3; ++dy_) \
        _Pragma("unroll") for (int j_ = 0; j_ < 2; ++j_) { \
            const int r_ = j_ + dy_; \
            acc[0][j_] = MFMA32(CUR##H[dy_][0], bH_[r_], acc[0][j_]); \
            acc[0][j_] = MFMA32(CUR##H[dy_][0], bL_[r_], acc[0][j_]); \
            acc[0][j_] = MFMA32(CUR##L[dy_][0], bH_[r_], acc[0][j_]); \
            acc[1][j_] = MFMA32(CUR##H[dy_][1], bH_[r_], acc[1][j_]); \
            acc[1][j_] = MFMA32(CUR##H[dy_][1], bL_[r_], acc[1][j_]); \
            acc[1][j_] = MFMA32(CUR##L[dy_][1], bH_[r_], acc[1][j_]); \
        } \
    __builtin_amdgcn_s_setprio(0); }

    // ---- prologue ----
    ISSUE_IN(0, 0);
    LOADA(A0, 0, 0);
    SCB; VWAIT12; BAR; SCB;

    // ---- chunk 0 (buf0) ----
    ISSUE_IN(1, 21760); LOADA(A1, 0, 1); PHASE(0, 0, A0);
    LOADA(A0, 0, 2);                     PHASE(0, 1, A1);
    LOADA(A1, 1, 0);                     PHASE(0, 2, A0);
    SCB; VWAIT12; BAR; SCB;
    // ---- chunk 1 (buf1) ----
    ISSUE_IN(2, 0);     LOADA(A0, 1, 1); PHASE(1, 0, A1);
    LOADA(A1, 1, 2);                     PHASE(1, 1, A0);
    LOADA(A0, 2, 0);                     PHASE(1, 2, A1);
    SCB; VWAIT12; BAR; SCB;
    // ---- chunk 2 (buf0) ----
    ISSUE_IN(3, 21760); LOADA(A1, 2, 1); PHASE(2, 0, A0);
    LOADA(A0, 2, 2);                     PHASE(2, 1, A1);
    LOADA(A1, 3, 0);                     PHASE(2, 2, A0);
    SCB; VWAIT12; BAR; SCB;
    // ---- chunk 3 (buf1) ----
    LOADA(A0, 3, 1); PHASE(3, 0, A1);
    LOADA(A1, 3, 2); PHASE(3, 1, A0);
    PHASE(3, 2, A1);

#undef ISSUE_IN
#undef LOADA
#undef PHASE

    // ---- epilogue: C/D col = ln(px), row = 8q + 4lh + (0..3), +32m ----
    #pragma unroll
    for (int m = 0; m < 2; ++m)
        #pragma unroll
        for (int j = 0; j < 2; ++j) {
            const int yo = y0 + 2 * wv + j;
            const int pixel = (yo << 8) + x0 + ln;
            #pragma unroll
            for (int q = 0; q < 4; ++q) {
                const int co0 = m * 32 + 8 * q + 4 * lh;
                float v0 = acc[m][j][4 * q + 0], v1 = acc[m][j][4 * q + 1];
                float v2 = acc[m][j][4 * q + 2], v3 = acc[m][j][4 * q + 3];
                const int cc_o = co0 >> 4, ch = co0 & 15;
                const size_t gbase = ((((size_t)(b * 4 + cc_o)) << 16) + pixel) * 32 + ch;
                if (EPI == 0) {
                    float4 al = *(const float4*)(aux + co0);
                    v0 = v0 > 0.f ? v0 : al.x * v0;
                    v1 = v1 > 0.f ? v1 : al.y * v1;
                    v2 = v2 > 0.f ? v2 : al.z * v2;
                    v3 = v3 > 0.f ? v3 : al.w * v3;
                } else if (EPI == 1) {
                    ushort4 rh = *(const ushort4*)(rCL + gbase);
                    ushort4 rl = *(const ushort4*)(rCL + gbase + 16);
                    v0 += b2f(rh.x) + b2f(rl.x);
                    v1 += b2f(rh.y) + b2f(rl.y);
                    v2 += b2f(rh.z) + b2f(rl.z);
                    v3 += b2f(rh.w) + b2f(rl.w);
                } else {
                    float4 bi = *(const float4*)(aux + co0);
                    float ob;
                    ob = v0 + bi.x; v0 = (ob > 0.f ? ob : 0.2f * ob) * SQRT2;
                    ob = v1 + bi.y; v1 = (ob > 0.f ? ob : 0.2f * ob) * SQRT2;
                    ob = v2 + bi.z; v2 = (ob > 0.f ? ob : 0.2f * ob) * SQRT2;
                    ob = v3 + bi.w; v3 = (ob > 0.f ? ob : 0.2f * ob) * SQRT2;
                }
                if (EPI == 2) {
                    const size_t sp = (size_t)pixel;
                    onchw[(((size_t)(b * 64 + co0 + 0)) << 16) + sp] = v0;
                    onchw[(((size_t)(b * 64 + co0 + 1)) << 16) + sp] = v1;
                    onchw[(((size_t)(b * 64 + co0 + 2)) << 16) + sp] = v2;
                    onchw[(((size_t)(b * 64 + co0 + 3)) << 16) + sp] = v3;
                } else {
                    ushort4 h4, l4;
                    splitv(v0, h4.x, l4.x); splitv(v1, h4.y, l4.y);
                    splitv(v2, h4.z, l4.z); splitv(v3, h4.w, l4.w);
                    *(ushort4*)(oCL + gbase) = h4;
                    *(ushort4*)(oCL + gbase + 16) = l4;
                }
            }
        }
}

// ---------------------------------------------------------------------------
// Host launch
// ---------------------------------------------------------------------------
extern "C" void kernel_launch(void* const* d_in, const int* in_sizes, int n_in,
                              void* d_out, int out_size, void* d_ws, size_t ws_size,
                              hipStream_t stream) {
    const float* x       = (const float*)d_in[0];
    const float* style   = (const float*)d_in[1];
    const float* w1a     = (const float*)d_in[2];
    const float* alpha1  = (const float*)d_in[3];
    const float* w1b     = (const float*)d_in[4];
    const float* w2a     = (const float*)d_in[5];
    const float* alpha2  = (const float*)d_in[6];
    const float* w2b     = (const float*)d_in[7];
    const float* mod_w   = (const float*)d_in[8];
    const float* mod_b   = (const float*)d_in[9];
    const float* conv_w  = (const float*)d_in[10];
    const float* fused_b = (const float*)d_in[11];
    float* out = (float*)d_out;

    char* ws = (char*)d_ws;
    float*  zbf   = (float*)ws;                  // 256 B zero buffer
    float*  sbuf  = (float*)(ws + 256);          // 512 f
    float*  demod = (float*)(ws + 2304);         // 512 f
    ushort* wfix  = (ushort*)(ws + 4352);        // 4 x 147456 B images
    ushort* wmod  = (ushort*)(ws + 594176);      // 8 x 147456 B
    char*   pl    = ws + 1774080;
    const size_t PAIRB = 134217728ull;           // one chunked-CL buffer (bytes)

    ushort* XP = (ushort*)pl;
    ushort* PB = (ushort*)(pl + PAIRB);
    ushort* PA;
    if (ws_size >= 1774080ull + 3 * PAIRB) PA = (ushort*)(pl + 2 * PAIRB);
    else                                   PA = (ushort*)d_out;  // rewritten by c5
    const ushort* zb = (const ushort*)zbf;

    // --- prep ---
    hipLaunchKernelGGL(zero_k, dim3(1), dim3(64), 0, stream, zbf);
    hipLaunchKernelGGL(tocl_k, dim3(BB * 1024), dim3(256), 0, stream, x, XP);
    hipLaunchKernelGGL(packw_k, dim3(288), dim3(256), 0, stream, w1a, wfix + 0 * 73728);
    hipLaunchKernelGGL(packw_k, dim3(288), dim3(256), 0, stream, w1b, wfix + 1 * 73728);
    hipLaunchKernelGGL(packw_k, dim3(288), dim3(256), 0, stream, w2a, wfix + 2 * 73728);
    hipLaunchKernelGGL(packw_k, dim3(288), dim3(256), 0, stream, w2b, wfix + 3 * 73728);
    hipLaunchKernelGGL(style_s_k, dim3(1), dim3(512), 0, stream, style, mod_w, mod_b, sbuf);
    hipLaunchKernelGGL(demod_k, dim3(1), dim3(512), 0, stream, conv_w, sbuf, demod);
    hipLaunchKernelGGL(packmod_k, dim3(2304), dim3(256), 0, stream, conv_w, sbuf, demod, wmod);

    // --- conv chain ---
    const dim3 cgrid(2048), cblk(256);
    // c1: t1 = prelu(conv(x, w1a))           XP -> PA
    hipLaunchKernelGGL((mconv_k<0, 0>), cgrid, cblk, 0, stream,
        XP, wfix + 0 * 73728, alpha1, (const ushort*)nullptr, PA, (float*)nullptr, zb);
    // c2: h1 = x + conv(t1, w1b)             PA -> PB  (resid XP)
    hipLaunchKernelGGL((mconv_k<1, 0>), cgrid, cblk, 0, stream,
        PA, wfix + 1 * 73728, (const float*)nullptr, XP, PB, (float*)nullptr, zb);
    // c3: t2 = prelu(conv(h1, w2a))          PB -> PA
    hipLaunchKernelGGL((mconv_k<0, 0>), cgrid, cblk, 0, stream,
        PB, wfix + 2 * 73728, alpha2, (const ushort*)nullptr, PA, (float*)nullptr, zb);
    // c4: h2 = h1 + conv(t2, w2b)            PA -> PB  (resid PB, same-index in-place)
    hipLaunchKernelGGL((mconv_k<1, 0>), cgrid, cblk, 0, stream,
        PA, wfix + 3 * 73728, (const float*)nullptr, PB, PB, (float*)nullptr, zb);
    // c5: out = fused_lrelu(modconv(h2)+b)   PB -> out (NCHW fp32)
    hipLaunchKernelGGL((mconv_k<2, 1>), cgrid, cblk, 0, stream,
        PB, wmod, fused_b, (const ushort*)nullptr, (ushort*)nullptr, out, zb);
}

// Round 10
// 922.797 us; speedup vs baseline: 1.2096x; 1.0306x over previous
//
#include <hip/hip_runtime.h>
#include <hip/hip_bf16.h>
#include <math.h>

#define BB 8
#define SS 512
#define LIN_SCALE 0.044194173824159216f   // 1/sqrt(512)
#define CONV_SCALE 0.041666666666666664f  // 1/sqrt(64*9)
#define SQRT2 1.4142135623730951f

typedef __attribute__((ext_vector_type(8))) short short8;
typedef __attribute__((ext_vector_type(16))) float f32x16;

__device__ __forceinline__ ushort bf16h(float v) {
    unsigned u = __float_as_uint(v);
    return (ushort)((u + 0x7fffu + ((u >> 16) & 1u)) >> 16);
}
__device__ __forceinline__ void splitv(float v, ushort& h, ushort& l) {
    h = bf16h(v);
    l = bf16h(v - __uint_as_float((unsigned)h << 16));
}
__device__ __forceinline__ float b2f(ushort u) { return __uint_as_float((unsigned)u << 16); }

// ---------------------------------------------------------------------------
// Global chunked-CL format (proven R8/R9): region (b, cc) = 65536 pixels; per
// pixel a 64B granule-quad: u16 [0..7]=H c0..7, [8..15]=H c8..15,
// [16..23]=L c0..7, [24..31]=L c8..15.
// ---------------------------------------------------------------------------

__global__ void zero_k(float* z) { z[threadIdx.x] = 0.f; }   // 64 thr -> 256 B

// NCHW fp32 -> chunked-CL bf16 hi/lo (proven R8)
__global__ __launch_bounds__(256) void tocl_k(const float* __restrict__ x,
                                              ushort* __restrict__ oCL) {
    __shared__ float tile[64][65];
    const int blk = blockIdx.x;                  // 8*256*4
    const int b = blk >> 10, rem = blk & 1023;
    const int y = rem >> 2, x0 = (rem & 3) << 6;
    const int tid = threadIdx.x, lane = tid & 63, g = tid >> 6;
    const float* xb = x + ((size_t)b << 22) + (y << 8) + x0;
    #pragma unroll
    for (int i = 0; i < 16; ++i) {
        int c = i * 4 + g;
        tile[c][lane] = xb[((size_t)c << 16) + lane];
    }
    __syncthreads();
    const int cc = tid >> 6, xx = tid & 63;
    ushort hh[16], ll[16];
    #pragma unroll
    for (int t = 0; t < 16; ++t) splitv(tile[cc * 16 + t][xx], hh[t], ll[t]);
    uint w[16];
    #pragma unroll
    for (int i = 0; i < 8; ++i) {
        w[i]     = (uint)hh[2 * i] | ((uint)hh[2 * i + 1] << 16);
        w[8 + i] = (uint)ll[2 * i] | ((uint)ll[2 * i + 1] << 16);
    }
    ushort* dst = oCL + ((((size_t)(b * 4 + cc)) << 16) + (y << 8) + x0 + xx) * 32;
    *(uint4*)(dst +  0) = make_uint4(w[0], w[1], w[2], w[3]);
    *(uint4*)(dst +  8) = make_uint4(w[4], w[5], w[6], w[7]);
    *(uint4*)(dst + 16) = make_uint4(w[8], w[9], w[10], w[11]);
    *(uint4*)(dst + 24) = make_uint4(w[12], w[13], w[14], w[15]);
}

// Weight image == LDS image (proven R8). ushort i: cc = i/18432; slot s;
// F = s>>6 = td*4 + pl*2 + m; u = s&63 = ln*2+lh; td = dx*3+dy.
__device__ __forceinline__ int wsrc_idx(int i, int& pl) {
    int e = i & 7;
    int j = (i % 18432) >> 3;
    int cc = i / 18432;
    int F = j >> 6, u = j & 63;
    int ln_ = u >> 1, lh_ = u & 1;
    int m = F & 1; pl = (F >> 1) & 1;
    int td = F >> 2;
    int dx = td / 3, dy = td - 3 * dx;
    int co = m * 32 + ln_;
    int ci = cc * 16 + lh_ * 8 + e;
    return (co * 64 + ci) * 9 + dy * 3 + dx;
}

__global__ void packw_k(const float* __restrict__ w, ushort* __restrict__ img) {
    int i = blockIdx.x * 256 + threadIdx.x;      // 73728
    if (i >= 73728) return;
    int pl; int src = wsrc_idx(i, pl);
    ushort h, l; splitv(w[src], h, l);
    img[i] = pl ? l : h;
}

__global__ void style_s_k(const float* __restrict__ style, const float* __restrict__ mod_w,
                          const float* __restrict__ mod_b, float* __restrict__ sbuf) {
    int tid = threadIdx.x;                       // 512
    int b = tid >> 6, cin = tid & 63;
    float acc = 0.f;
    for (int j = 0; j < SS; ++j) acc += style[b * SS + j] * mod_w[cin * SS + j];
    sbuf[b * 64 + cin] = acc * LIN_SCALE + mod_b[cin];
}

__global__ void demod_k(const float* __restrict__ conv_w, const float* __restrict__ sbuf,
                        float* __restrict__ demod) {
    int tid = threadIdx.x;                       // 512
    int b = tid >> 6, cout = tid & 63;
    float sum = 0.f;
    for (int cin = 0; cin < 64; ++cin) {
        float m = CONV_SCALE * sbuf[b * 64 + cin];
        const float* wp = conv_w + (cout * 64 + cin) * 9;
        #pragma unroll
        for (int k = 0; k < 9; ++k) { float v = wp[k] * m; sum += v * v; }
    }
    demod[b * 64 + cout] = 1.0f / sqrtf(sum + 1e-8f);
}

__global__ void packmod_k(const float* __restrict__ conv_w, const float* __restrict__ sbuf,
                          const float* __restrict__ demod, ushort* __restrict__ img) {
    int i = blockIdx.x * 256 + threadIdx.x;      // 589824
    if (i >= 589824) return;
    int b = i / 73728, ii = i % 73728;
    int pl; int src = wsrc_idx(ii, pl);
    int co = src / 576; int ci = (src / 9) % 64;
    float v = CONV_SCALE * conv_w[src] * sbuf[b * 64 + ci] * demod[b * 64 + co];
    ushort h, l; splitv(v, h, l);
    img[i] = pl ? l : h;
}

// ---------------------------------------------------------------------------
// MFMA conv: 3x3 C64->C64 SAME. Chunked-CL bf16 H/L input.
// Block 256 thr = 4 waves; tile 16 rows x 32 px; 64 couts. Wave wv: output
// rows 4wv..4wv+3 (4 N x 2 M = 8 dep-chains). K chunked 16 cins, 12 phases.
// Weights: LDS dbuf 2x36864 via global_load_lds (vmcnt) ; A-reads via lgkm.
// Input B: DIRECT global->VGPR (chunked-CL, L1/L2 dx-reuse); H prefetched
// one phase ahead in registers, L loaded in-phase (same 64B line as H).
// One counted vmcnt(6)+barrier per chunk.  LDS 73728 -> 2 blocks/CU.
// EPI: 0 = PReLU->CL, 1 = +resid(CL)->CL, 2 = fusedLReLU->NCHW fp32.
// ---------------------------------------------------------------------------
#define GLDS(gsrc, ldst) __builtin_amdgcn_global_load_lds( \
    (const __attribute__((address_space(1))) unsigned int*)(gsrc), \
    (__attribute__((address_space(3))) unsigned int*)(ldst), 16, 0, 0)

#define VWAIT6 asm volatile("s_waitcnt vmcnt(6)" ::: "memory")
#define BAR    __builtin_amdgcn_s_barrier()
#define SCB    __builtin_amdgcn_sched_barrier(0)
#define MFMA32(a, bb, c) __builtin_amdgcn_mfma_f32_32x32x16_bf16(a, bb, c, 0, 0, 0)

template <int EPI, int PERB>
__global__ __launch_bounds__(256, 2)
void mconv_k(const ushort* __restrict__ inCL, const ushort* __restrict__ wimg,
             const float* __restrict__ aux, const ushort* __restrict__ rCL,
             ushort* __restrict__ oCL, float* __restrict__ onchw,
             const ushort* __restrict__ zb) {
    __shared__ __align__(16) char lds[73728];    // weight dbuf 2 x 36864
    const int tid = threadIdx.x;
    const int orig = blockIdx.x;
    const int blk = (orig & 7) * 128 + (orig >> 3);   // XCD swizzle (1024 % 8 == 0)
    const int b = blk >> 7, t7 = blk & 127;
    const int y0 = (t7 >> 3) << 4, x0 = (t7 & 7) << 5;
    const int wv = tid >> 6, l = tid & 63, ln = l & 31, lh = l >> 5;

    const ushort* wsrc = wimg + (PERB ? (size_t)b * 73728 : 0);
    const int gx = x0 + ln - 1;                  // +DX at use
    const size_t breg = (size_t)(b * 4) << 16;   // + cc<<16

    f32x16 acc[2][4];
    #pragma unroll
    for (int m = 0; m < 2; ++m)
        #pragma unroll
        for (int j = 0; j < 4; ++j) acc[m][j] = (f32x16)(0.0f);

    short8 B0[6], B1[6];

#define ISSUE_W(cc, bo) { \
    const ushort* wsB_ = wsrc + (cc) * 18432; \
    _Pragma("unroll") for (int r_ = 0; r_ < 9; ++r_) \
        GLDS(wsB_ + r_ * 2048 + tid * 8, lds + (bo) + r_ * 4096 + (tid & 192) * 16); }

// prefetch H fragments for phase (CC,DX) into bank BNK
#define PRE_H(BNK, CC, DX) { \
    _Pragma("unroll") for (int r_ = 0; r_ < 6; ++r_) { \
        const int gy_ = y0 + 4 * wv - 1 + r_; \
        const int gxx_ = gx + (DX); \
        const bool ok_ = ((unsigned)gy_ < 256u) & ((unsigned)gxx_ < 256u); \
        const ushort* a_ = ok_ \
            ? inCL + ((breg + ((size_t)(CC) << 16) + (gy_ << 8) + gxx_) * 32 + lh * 8) \
            : zb; \
        BNK[r_] = *(const short8*)a_; \
    } }

// in-phase L fragments (same 64B lines as H -> L1 hits)
#define LOAD_L(DST, CC, DX) { \
    _Pragma("unroll") for (int r_ = 0; r_ < 6; ++r_) { \
        const int gy_ = y0 + 4 * wv - 1 + r_; \
        const int gxx_ = gx + (DX); \
        const bool ok_ = ((unsigned)gy_ < 256u) & ((unsigned)gxx_ < 256u); \
        const ushort* a_ = ok_ \
            ? inCL + ((breg + ((size_t)(CC) << 16) + (gy_ << 8) + gxx_) * 32 + 16 + lh * 8) \
            : zb; \
        DST[r_] = *(const short8*)a_; \
    } }

#define PH(p, CUR, NXT) { \
    const int C_ = (p) / 3, DX_ = (p) % 3; \
    if ((p) < 11) PRE_H(NXT, ((p) + 1) / 3, ((p) + 1) % 3); \
    short8 bl_[6]; \
    LOAD_L(bl_, C_, DX_); \
    const char* wb_ = lds + (C_ & 1) * 36864; \
    __builtin_amdgcn_s_setprio(1); \
    _Pragma("unroll") for (int dy_ = 0; dy_ < 3; ++dy_) { \
        const char* wa_ = wb_ + (DX_ * 3 + dy_) * 4096 + (ln * 2 + lh) * 16; \
        const short8 aH0_ = *(const short8*)(wa_); \
        const short8 aH1_ = *(const short8*)(wa_ + 1024); \
        const short8 aL0_ = *(const short8*)(wa_ + 2048); \
        const short8 aL1_ = *(const short8*)(wa_ + 3072); \
        _Pragma("unroll") for (int j_ = 0; j_ < 4; ++j_) { \
            const int r_ = j_ + dy_; \
            acc[0][j_] = MFMA32(aH0_, CUR[r_], acc[0][j_]); \
            acc[0][j_] = MFMA32(aH0_, bl_[r_], acc[0][j_]); \
            acc[0][j_] = MFMA32(aL0_, CUR[r_], acc[0][j_]); \
            acc[1][j_] = MFMA32(aH1_, CUR[r_], acc[1][j_]); \
            acc[1][j_] = MFMA32(aH1_, bl_[r_], acc[1][j_]); \
            acc[1][j_] = MFMA32(aL1_, CUR[r_], acc[1][j_]); \
        } \
    } \
    __builtin_amdgcn_s_setprio(0); \
    if (DX_ == 0 && C_ < 3) { ISSUE_W(C_ + 1, ((C_ + 1) & 1) * 36864); } \
    if (DX_ == 2 && (p) < 11) { SCB; VWAIT6; BAR; SCB; } }

    // ---- prologue: weights chunk 0 + H bank for phase 0 ----
    ISSUE_W(0, 0);
    PRE_H(B0, 0, 0);
    SCB; VWAIT6; BAR; SCB;

    PH(0, B0, B1);  PH(1, B1, B0);  PH(2, B0, B1);
    PH(3, B1, B0);  PH(4, B0, B1);  PH(5, B1, B0);
    PH(6, B0, B1);  PH(7, B1, B0);  PH(8, B0, B1);
    PH(9, B1, B0);  PH(10, B0, B1); PH(11, B1, B0);

#undef ISSUE_W
#undef PRE_H
#undef LOAD_L
#undef PH

    // ---- epilogue: C/D col = ln(px), row = 8q + 4lh + (0..3), +32m ----
    #pragma unroll
    for (int m = 0; m < 2; ++m)
        #pragma unroll
        for (int j = 0; j < 4; ++j) {
            const int yo = y0 + 4 * wv + j;
            const int pixel = (yo << 8) + x0 + ln;
            #pragma unroll
            for (int q = 0; q < 4; ++q) {
                const int co0 = m * 32 + 8 * q + 4 * lh;
                float v0 = acc[m][j][4 * q + 0], v1 = acc[m][j][4 * q + 1];
                float v2 = acc[m][j][4 * q + 2], v3 = acc[m][j][4 * q + 3];
                const int cc_o = co0 >> 4, ch = co0 & 15;
                const size_t gbase = ((((size_t)(b * 4 + cc_o)) << 16) + pixel) * 32 + ch;
                if (EPI == 0) {
                    float4 al = *(const float4*)(aux + co0);
                    v0 = v0 > 0.f ? v0 : al.x * v0;
                    v1 = v1 > 0.f ? v1 : al.y * v1;
                    v2 = v2 > 0.f ? v2 : al.z * v2;
                    v3 = v3 > 0.f ? v3 : al.w * v3;
                } else if (EPI == 1) {
                    ushort4 rh = *(const ushort4*)(rCL + gbase);
                    ushort4 rl = *(const ushort4*)(rCL + gbase + 16);
                    v0 += b2f(rh.x) + b2f(rl.x);
                    v1 += b2f(rh.y) + b2f(rl.y);
                    v2 += b2f(rh.z) + b2f(rl.z);
                    v3 += b2f(rh.w) + b2f(rl.w);
                } else {
                    float4 bi = *(const float4*)(aux + co0);
                    float ob;
                    ob = v0 + bi.x; v0 = (ob > 0.f ? ob : 0.2f * ob) * SQRT2;
                    ob = v1 + bi.y; v1 = (ob > 0.f ? ob : 0.2f * ob) * SQRT2;
                    ob = v2 + bi.z; v2 = (ob > 0.f ? ob : 0.2f * ob) * SQRT2;
                    ob = v3 + bi.w; v3 = (ob > 0.f ? ob : 0.2f * ob) * SQRT2;
                }
                if (EPI == 2) {
                    const size_t sp = (size_t)pixel;
                    onchw[(((size_t)(b * 64 + co0 + 0)) << 16) + sp] = v0;
                    onchw[(((size_t)(b * 64 + co0 + 1)) << 16) + sp] = v1;
                    onchw[(((size_t)(b * 64 + co0 + 2)) << 16) + sp] = v2;
                    onchw[(((size_t)(b * 64 + co0 + 3)) << 16) + sp] = v3;
                } else {
                    ushort4 h4, l4;
                    splitv(v0, h4.x, l4.x); splitv(v1, h4.y, l4.y);
                    splitv(v2, h4.z, l4.z); splitv(v3, h4.w, l4.w);
                    *(ushort4*)(oCL + gbase) = h4;
                    *(ushort4*)(oCL + gbase + 16) = l4;
                }
            }
        }
}

// ---------------------------------------------------------------------------
// Host launch
// ---------------------------------------------------------------------------
extern "C" void kernel_launch(void* const* d_in, const int* in_sizes, int n_in,
                              void* d_out, int out_size, void* d_ws, size_t ws_size,
                              hipStream_t stream) {
    const float* x       = (const float*)d_in[0];
    const float* style   = (const float*)d_in[1];
    const float* w1a     = (const float*)d_in[2];
    const float* alpha1  = (const float*)d_in[3];
    const float* w1b     = (const float*)d_in[4];
    const float* w2a     = (const float*)d_in[5];
    const float* alpha2  = (const float*)d_in[6];
    const float* w2b     = (const float*)d_in[7];
    const float* mod_w   = (const float*)d_in[8];
    const float* mod_b   = (const float*)d_in[9];
    const float* conv_w  = (const float*)d_in[10];
    const float* fused_b = (const float*)d_in[11];
    float* out = (float*)d_out;

    char* ws = (char*)d_ws;
    float*  zbf   = (float*)ws;                  // 256 B zero buffer
    float*  sbuf  = (float*)(ws + 256);          // 512 f
    float*  demod = (float*)(ws + 2304);         // 512 f
    ushort* wfix  = (ushort*)(ws + 4352);        // 4 x 147456 B images
    ushort* wmod  = (ushort*)(ws + 594176);      // 8 x 147456 B
    char*   pl    = ws + 1774080;
    const size_t PAIRB = 134217728ull;           // one chunked-CL buffer (bytes)

    ushort* XP = (ushort*)pl;
    ushort* PB = (ushort*)(pl + PAIRB);
    ushort* PA;
    if (ws_size >= 1774080ull + 3 * PAIRB) PA = (ushort*)(pl + 2 * PAIRB);
    else                                   PA = (ushort*)d_out;  // rewritten by c5
    const ushort* zb = (const ushort*)zbf;

    // --- prep ---
    hipLaunchKernelGGL(zero_k, dim3(1), dim3(64), 0, stream, zbf);
    hipLaunchKernelGGL(tocl_k, dim3(BB * 1024), dim3(256), 0, stream, x, XP);
    hipLaunchKernelGGL(packw_k, dim3(288), dim3(256), 0, stream, w1a, wfix + 0 * 73728);
    hipLaunchKernelGGL(packw_k, dim3(288), dim3(256), 0, stream, w1b, wfix + 1 * 73728);
    hipLaunchKernelGGL(packw_k, dim3(288), dim3(256), 0, stream, w2a, wfix + 2 * 73728);
    hipLaunchKernelGGL(packw_k, dim3(288), dim3(256), 0, stream, w2b, wfix + 3 * 73728);
    hipLaunchKernelGGL(style_s_k, dim3(1), dim3(512), 0, stream, style, mod_w, mod_b, sbuf);
    hipLaunchKernelGGL(demod_k, dim3(1), dim3(512), 0, stream, conv_w, sbuf, demod);
    hipLaunchKernelGGL(packmod_k, dim3(2304), dim3(256), 0, stream, conv_w, sbuf, demod, wmod);

    // --- conv chain ---
    const dim3 cgrid(1024), cblk(256);
    // c1: t1 = prelu(conv(x, w1a))           XP -> PA
    hipLaunchKernelGGL((mconv_k<0, 0>), cgrid, cblk, 0, stream,
        XP, wfix + 0 * 73728, alpha1, (const ushort*)nullptr, PA, (float*)nullptr, zb);
    // c2: h1 = x + conv(t1, w1b)             PA -> PB  (resid XP)
    hipLaunchKernelGGL((mconv_k<1, 0>), cgrid, cblk, 0, stream,
        PA, wfix + 1 * 73728, (const float*)nullptr, XP, PB, (float*)nullptr, zb);
    // c3: t2 = prelu(conv(h1, w2a))          PB -> PA
    hipLaunchKernelGGL((mconv_k<0, 0>), cgrid, cblk, 0, stream,
        PB, wfix + 2 * 73728, alpha2, (const ushort*)nullptr, PA, (float*)nullptr, zb);
    // c4: h2 = h1 + conv(t2, w2b)            PA -> PB  (resid PB, same-index in-place)
    hipLaunchKernelGGL((mconv_k<1, 0>), cgrid, cblk, 0, stream,
        PA, wfix + 3 * 73728, (const float*)nullptr, PB, PB, (float*)nullptr, zb);
    // c5: out = fused_lrelu(modconv(h2)+b)   PB -> out (NCHW fp32)
    hipLaunchKernelGGL((mconv_k<2, 1>), cgrid, cblk, 0, stream,
        PB, wmod, fused_b, (const ushort*)nullptr, (ushort*)nullptr, out, zb);
}